// Round 2
// baseline (190.932 us; speedup 1.0000x reference)
//
#include <hip/hip_runtime.h>
#include <cstdint>
#include <cstddef>

namespace {

constexpr int NCLS   = 32;
constexpr int KSHOT  = 5;
constexpr int FDIM   = 21168;   // 3*84*84
constexpr int KPAD   = 21248;   // 332 * 64
constexpr int DDIM   = 1600;
constexpr int NROW   = 512;     // 32 proto + 480 query
constexpr int NQROW  = 480;
constexpr int NKT    = 332;     // K tiles of 64
constexpr int MAXS   = 19;      // split-K (13*19 = 247 blocks, 1/CU)

using short8 = __attribute__((ext_vector_type(8))) short;
using f32x4  = __attribute__((ext_vector_type(4))) float;

__device__ __forceinline__ unsigned f2bf(float x) {
    union { float f; unsigned u; } v; v.f = x;
    unsigned r = v.u + 0x7fffu + ((v.u >> 16) & 1u);   // RNE
    return r >> 16;
}

__device__ __forceinline__ uint4 pack8(const float* v) {
    uint4 p;
    p.x = f2bf(v[0]) | (f2bf(v[1]) << 16);
    p.y = f2bf(v[2]) | (f2bf(v[3]) << 16);
    p.z = f2bf(v[4]) | (f2bf(v[5]) << 16);
    p.w = f2bf(v[6]) | (f2bf(v[7]) << 16);
    return p;
}

// ---------------------------------------------------------------------------
// Kernel 1: build A_bf16 [512][KPAD]; rows 0..31 = 5-shot mean, rest = query.
// ---------------------------------------------------------------------------
__global__ void prep_A(const float* __restrict__ supp,
                       const float* __restrict__ query,
                       unsigned short* __restrict__ A) {
    const int units = NROW * (KPAD / 4);
    for (int u = blockIdx.x * blockDim.x + threadIdx.x; u < units;
         u += gridDim.x * blockDim.x) {
        const int r = u / (KPAD / 4);
        const int c = (u % (KPAD / 4)) * 4;
        float4 v = make_float4(0.f, 0.f, 0.f, 0.f);
        if (c < FDIM) {   // FDIM % 4 == 0
            if (r < NCLS) {
                const float* s = supp + (size_t)r * KSHOT * FDIM + c;
                float4 a0 = *(const float4*)(s);
                float4 a1 = *(const float4*)(s + FDIM);
                float4 a2 = *(const float4*)(s + 2 * FDIM);
                float4 a3 = *(const float4*)(s + 3 * FDIM);
                float4 a4 = *(const float4*)(s + 4 * FDIM);
                v.x = (a0.x + a1.x + a2.x + a3.x + a4.x) * 0.2f;
                v.y = (a0.y + a1.y + a2.y + a3.y + a4.y) * 0.2f;
                v.z = (a0.z + a1.z + a2.z + a3.z + a4.z) * 0.2f;
                v.w = (a0.w + a1.w + a2.w + a3.w + a4.w) * 0.2f;
            } else {
                v = *(const float4*)(query + (size_t)(r - NCLS) * FDIM + c);
            }
        }
        ushort4 o;
        o.x = (unsigned short)f2bf(v.x); o.y = (unsigned short)f2bf(v.y);
        o.z = (unsigned short)f2bf(v.z); o.w = (unsigned short)f2bf(v.w);
        *(ushort4*)(A + (size_t)r * KPAD + c) = o;
    }
}

// ---------------------------------------------------------------------------
// Kernel 2: GEMM  Cpart[s] += A[512][K-range] @ bf16(W[K-range][128-col tile])
// BM=512 (full M), BN=128, BK=64. 8 waves stack m exclusively (wave tile
// 64x128): A fragments loaded straight global->reg (no LDS, no barrier dep).
// B: fp32 W prefetched to regs for tile t+1 while MFMAs run on tile t,
// converted + written XOR-swizzled into the other LDS buffer. One barrier
// per K-tile; counted vmcnt keeps the W prefetch in flight across MFMA.
// ---------------------------------------------------------------------------
__global__ __launch_bounds__(512, 2) void gemm2(
        const unsigned short* __restrict__ A,   // [512][KPAD] bf16 bits
        const float* __restrict__ W,            // [FDIM][DDIM] fp32
        float* __restrict__ Cpart, int S) {     // [S][512][DDIM]
    __shared__ unsigned short Bl[2][128 * 64];  // XOR-swizzled k-blocks

    const int b  = blockIdx.x;
    const int nt = b % 13;
    const int s  = b / 13;
    const int n0 = nt * 128;
    const int t0 = (NKT * s) / S;
    const int t1 = (NKT * (s + 1)) / S;

    const int tid  = threadIdx.x;
    const int lane = tid & 63;
    const int wid  = tid >> 6;       // 0..7 : m-wave
    const int g    = lane >> 4;      // 0..3 : k sub-block
    const int r15  = lane & 15;

    // B staging role: bn = column 0..127, bw = k-group of 16
    const int bn = tid & 127;
    const int bw = tid >> 7;         // 0..3
    const int ncol = n0 + bn;
    const bool nok = ncol < DDIM;
    const float* Wp = W + ncol;
    const int woff0 = bn * 64 + (((bw * 2 + 0) ^ (bn & 7)) * 8);
    const int woff1 = bn * 64 + (((bw * 2 + 1) ^ (bn & 7)) * 8);

    // per-lane A row pointers (loop-invariant)
    const unsigned short* Arow[4];
    #pragma unroll
    for (int ms = 0; ms < 4; ++ms)
        Arow[ms] = A + (size_t)(wid * 64 + ms * 16 + r15) * KPAD + g * 8;

    f32x4 acc[4][8];
    #pragma unroll
    for (int i = 0; i < 4; ++i)
        #pragma unroll
        for (int j = 0; j < 8; ++j)
            acc[i][j] = (f32x4){0.f, 0.f, 0.f, 0.f};

    // prologue: stage B for tile t0 into Bl[0]
    {
        const int k0 = t0 * 64;
        float wv[16];
        #pragma unroll
        for (int i = 0; i < 16; ++i) {
            const int kg = k0 + bw * 16 + i;
            wv[i] = (nok && kg < FDIM) ? Wp[(size_t)kg * DDIM] : 0.f;
        }
        *(uint4*)(&Bl[0][woff0]) = pack8(wv);
        *(uint4*)(&Bl[0][woff1]) = pack8(wv + 8);
    }
    __syncthreads();

    int cur = 0;
    for (int t = t0; t < t1; ++t) {
        const int k0 = t * 64;
        // A fragment loads first (compiler's vmcnt for MFMA then leaves the
        // W prefetch below in flight)
        short8 af[2][4];
        #pragma unroll
        for (int kk = 0; kk < 2; ++kk)
            #pragma unroll
            for (int ms = 0; ms < 4; ++ms)
                af[kk][ms] = *(const short8*)(Arow[ms] + k0 + kk * 32);

        // W prefetch for tile t+1 (regs only; consumed after the MFMAs)
        const bool more = (t + 1 < t1);
        float wv[16];
        if (more) {
            const int kn = k0 + 64;
            #pragma unroll
            for (int i = 0; i < 16; ++i) {
                const int kg = kn + bw * 16 + i;
                wv[i] = (nok && kg < FDIM) ? Wp[(size_t)kg * DDIM] : 0.f;
            }
        }

        // compute on Bl[cur]
        #pragma unroll
        for (int kk = 0; kk < 2; ++kk) {
            short8 bfr[8];
            #pragma unroll
            for (int ns = 0; ns < 8; ++ns) {
                const int Rn  = ns * 16 + r15;
                const int pos = (kk * 4 + g) ^ (Rn & 7);
                bfr[ns] = *(const short8*)(&Bl[cur][Rn * 64 + pos * 8]);
            }
            #pragma unroll
            for (int ms = 0; ms < 4; ++ms)
                #pragma unroll
                for (int ns = 0; ns < 8; ++ns)
                    acc[ms][ns] = __builtin_amdgcn_mfma_f32_16x16x32_bf16(
                        af[kk][ms], bfr[ns], acc[ms][ns], 0, 0, 0);
        }

        // convert + write next B tile into the other buffer
        if (more) {
            *(uint4*)(&Bl[cur ^ 1][woff0]) = pack8(wv);
            *(uint4*)(&Bl[cur ^ 1][woff1]) = pack8(wv + 8);
        }
        __syncthreads();
        cur ^= 1;
    }

    // epilogue: write split partial
    float* Cp = Cpart + (size_t)s * NROW * DDIM;
    #pragma unroll
    for (int ms = 0; ms < 4; ++ms) {
        const int row = wid * 64 + ms * 16 + g * 4;
        #pragma unroll
        for (int ns = 0; ns < 8; ++ns) {
            const int col = n0 + ns * 16 + r15;
            if (col < DDIM) {
                #pragma unroll
                for (int r = 0; r < 4; ++r)
                    Cp[(size_t)(row + r) * DDIM + col] = acc[ms][ns][r];
            }
        }
    }
}

// ---------------------------------------------------------------------------
// Kernel 3: sum S split partials -> C, plus per-row inverse norm.
// ---------------------------------------------------------------------------
__global__ void reduce_norm(const float* __restrict__ Cpart,
                            float* __restrict__ C,
                            float* __restrict__ inv_norm, int S) {
    const int row = blockIdx.x;
    const int tid = threadIdx.x;
    float acc = 0.f;
    for (int c = tid; c < DDIM; c += 256) {
        float v = 0.f;
        for (int s2 = 0; s2 < S; ++s2)
            v += Cpart[((size_t)s2 * NROW + row) * DDIM + c];
        C[(size_t)row * DDIM + c] = v;
        acc += v * v;
    }
    __shared__ float red[4];
    #pragma unroll
    for (int off = 32; off > 0; off >>= 1) acc += __shfl_xor(acc, off);
    if ((tid & 63) == 0) red[tid >> 6] = acc;
    __syncthreads();
    if (tid == 0) {
        float a = red[0] + red[1] + red[2] + red[3];
        inv_norm[row] = 1.f / fmaxf(sqrtf(a), 1e-8f);
    }
}

// ---------------------------------------------------------------------------
// Kernel 4: fused cosine-sim (480x32) + log_softmax. One block per query row.
// ---------------------------------------------------------------------------
__global__ void simlog(const float* __restrict__ C,
                       const float* __restrict__ inv_norm,
                       float* __restrict__ out) {
    __shared__ float qs[DDIM];
    __shared__ float sims[NCLS];
    const int r = blockIdx.x;
    const int tid = threadIdx.x;
    const float* qrow = C + (size_t)(NCLS + r) * DDIM;
    for (int c = tid; c < DDIM; c += 256) qs[c] = qrow[c];
    __syncthreads();
    const float invq = inv_norm[NCLS + r];
    const int lane = tid & 63, w = tid >> 6;
    #pragma unroll
    for (int j = 0; j < 8; ++j) {
        const int p = w * 8 + j;
        const float* prow = C + (size_t)p * DDIM;
        float d = 0.f;
        for (int c = lane; c < DDIM; c += 64) d += qs[c] * prow[c];
        #pragma unroll
        for (int off = 32; off > 0; off >>= 1) d += __shfl_xor(d, off);
        if (lane == 0) sims[p] = d * invq * inv_norm[p];
    }
    __syncthreads();
    if (w == 0) {
        float v = (lane < NCLS) ? sims[lane] : -1e30f;
        float m = v;
        #pragma unroll
        for (int off = 32; off > 0; off >>= 1) m = fmaxf(m, __shfl_xor(m, off));
        float e = (lane < NCLS) ? expf(v - m) : 0.f;
        float ss = e;
        #pragma unroll
        for (int off = 32; off > 0; off >>= 1) ss += __shfl_xor(ss, off);
        if (lane < NCLS) out[(size_t)r * NCLS + lane] = v - m - logf(ss);
    }
}

} // anonymous namespace

// ws layout (bytes):
//   A_bf16 : NROW*KPAD*2            = 21,757,952
//   Cpart  : S*NROW*DDIM*4          = S * 3,276,800   (S = 19 -> 62,259,200)
//   C      : NROW*DDIM*4            =  3,276,800
//   invn   : 4,096
// S=19 total ~87.3 MB; S auto-shrinks if ws_size is smaller.

extern "C" void kernel_launch(void* const* d_in, const int* in_sizes, int n_in,
                              void* d_out, int out_size, void* d_ws, size_t ws_size,
                              hipStream_t stream) {
    const float* supp  = (const float*)d_in[0];
    const float* query = (const float*)d_in[1];
    const float* Wenc  = (const float*)d_in[2];
    float* out = (float*)d_out;

    const size_t slot   = (size_t)NROW * DDIM * 4;
    const size_t fixedA = (size_t)NROW * KPAD * 2;
    int S = MAXS;
    if (ws_size) {
        while (S > 1 && fixedA + (size_t)S * slot + slot + 4096 > ws_size) --S;
    }

    char* ws = (char*)d_ws;
    unsigned short* A = (unsigned short*)ws;
    float* Cpart    = (float*)(ws + fixedA);
    float* C        = (float*)(ws + fixedA + (size_t)S * slot);
    float* inv_norm = (float*)(ws + fixedA + (size_t)(S + 1) * slot);

    hipLaunchKernelGGL(prep_A, dim3(2048), dim3(256), 0, stream, supp, query, A);
    hipLaunchKernelGGL(gemm2, dim3(13 * S), dim3(512), 0, stream,
                       A, Wenc, Cpart, S);
    hipLaunchKernelGGL(reduce_norm, dim3(NROW), dim3(256), 0, stream,
                       Cpart, C, inv_norm, S);
    hipLaunchKernelGGL(simlog, dim3(NQROW), dim3(256), 0, stream,
                       C, inv_norm, out);
}